// Round 1
// baseline (196.216 us; speedup 1.0000x reference)
//
#include <hip/hip_runtime.h>
#include <math.h>

#define BB 4
#define SS 8192
#define HH 2048
#define EE 16
#define BRD_ 256
#define BSZ 1024   /* block size from _adjust(8192) */
#define NN 8       /* SS/BSZ */
#define NB 32      /* BB*NN */
#define MAXTOK 1720 /* int(8192*0.21000000000000002) */
#define KBUD 1
#define HHALF 1024

// ---------------- K1: block mean partial sums (memory-bound floor) ----------------
__global__ __launch_bounds__(256) void k_bmean(const float* __restrict__ x,
                                               double* __restrict__ part, int TC, int rows) {
  int wg = blockIdx.x;
  int bn = wg / TC, tc = wg - bn * TC;
  int b = bn >> 3, n = bn & 7;
  int tid = threadIdx.x;
  const float* base = x + ((size_t)(b * SS + n * BSZ + tc * rows) * HH);
  double a0=0,a1=0,a2=0,a3=0,a4=0,a5=0,a6=0,a7=0;
  for (int t = 0; t < rows; ++t) {
    const float4* r = (const float4*)(base + (size_t)t * HH);
    float4 u = r[tid];        // h = tid*4 .. +3
    float4 v = r[tid + 256];  // h = 1024 + tid*4 .. +3
    a0 += u.x; a1 += u.y; a2 += u.z; a3 += u.w;
    a4 += v.x; a5 += v.y; a6 += v.z; a7 += v.w;
  }
  double* p = part + ((size_t)bn * TC + tc) * HH;
  int hA = tid * 4, hB = 1024 + tid * 4;
  p[hA] = a0; p[hA+1] = a1; p[hA+2] = a2; p[hA+3] = a3;
  p[hB] = a4; p[hB+1] = a5; p[hB+2] = a6; p[hB+3] = a7;
}

// ---------------- K2: block router (fp64): reduce -> @bw1 -> LN -> gelu -> @bw2 -> softmax/entropy/argmax
__global__ __launch_bounds__(256) void k_router(const double* __restrict__ part, int TC,
    const float* __restrict__ bw1, const float* __restrict__ bb1,
    const float* __restrict__ lng, const float* __restrict__ lnb,
    const float* __restrict__ bw2, const float* __restrict__ bb2,
    double* __restrict__ ent, float* __restrict__ bwv, int* __restrict__ bwi) {
  __shared__ double br[HH];     // block_repr (mean), 16 KB
  __shared__ double tg[BRD_];   // gelu output
  __shared__ double red[4];
  __shared__ double l2[EE];
  __shared__ double bcast;
  int bn = blockIdx.x, tid = threadIdx.x;

  for (int k = 0; k < 8; ++k) {
    int h = tid + k * 256;
    double s = 0;
    for (int tc = 0; tc < TC; ++tc) s += part[((size_t)bn * TC + tc) * HH + h];
    br[h] = s * (1.0 / BSZ);
  }
  __syncthreads();

  // GEMM1: each thread computes output column j=tid (K=2048)
  double a = (double)bb1[tid];
  for (int k = 0; k < HH; ++k) a += br[k] * (double)bw1[k * BRD_ + tid];

  // LayerNorm over 256 outputs (eps=1e-5, population var)
  double v = a;
  for (int o = 32; o; o >>= 1) v += __shfl_down(v, o);
  if ((tid & 63) == 0) red[tid >> 6] = v;
  __syncthreads();
  if (tid == 0) bcast = (red[0] + red[1] + red[2] + red[3]) * (1.0 / BRD_);
  __syncthreads();
  double m = bcast;
  double d = a - m;
  v = d * d;
  for (int o = 32; o; o >>= 1) v += __shfl_down(v, o);
  if ((tid & 63) == 0) red[tid >> 6] = v;
  __syncthreads();
  if (tid == 0) bcast = (red[0] + red[1] + red[2] + red[3]) * (1.0 / BRD_);
  __syncthreads();
  double var = bcast;
  double xn = d / sqrt(var + 1e-5) * (double)lng[tid] + (double)lnb[tid];
  // exact GELU (approximate=False)
  tg[tid] = 0.5 * xn * (1.0 + erf(xn * 0.7071067811865476));
  __syncthreads();

  // GEMM2: 16 experts, K=256
  if (tid < EE) {
    double acc = (double)bb2[tid];
    for (int j = 0; j < BRD_; ++j) acc += tg[j] * (double)bw2[j * EE + tid];
    l2[tid] = acc;
  }
  __syncthreads();

  if (tid == 0) {
    double mx = l2[0];
    for (int e = 1; e < EE; ++e) mx = fmax(mx, l2[e]);
    double se = 0, p[EE];
    for (int e = 0; e < EE; ++e) { p[e] = exp(l2[e] - mx); se += p[e]; }
    double inv = 1.0 / se, entv = 0, mp = -1; int ai = 0;
    for (int e = 0; e < EE; ++e) {
      double pr = p[e] * inv;
      if (pr > mp) { mp = pr; ai = e; }   // first-max, matches argmax
      double q = pr + 1e-10;
      entv -= q * log(q);
    }
    entv /= log(16.0);
    ent[bn] = entv; bwv[bn] = (float)mp; bwi[bn] = ai;
  }
}

// ---------------- K3: mask logic (serial, 32 elements) ----------------
__global__ void k_flags(const double* __restrict__ ent, int* __restrict__ flags) {
  if (threadIdx.x != 0 || blockIdx.x != 0) return;
  const double THR = 0.6 * 1.1;  // 0.66000000000000003
  bool m1[NB]; int th = 0;
  for (int i = 0; i < NB; ++i) { m1[i] = ent[i] > THR; th += m1[i] ? 1 : 0; }
  // kth = KBUD-th largest among mask1-selected entropies (sorted desc, -inf padded)
  double a[NB];
  for (int i = 0; i < NB; ++i) a[i] = m1[i] ? ent[i] : -INFINITY;
  for (int i = 1; i < NB; ++i) {
    double vv = a[i]; int j = i - 1;
    while (j >= 0 && a[j] < vv) { a[j + 1] = a[j]; --j; }
    a[j + 1] = vv;
  }
  double kth = a[KBUD - 1];
  bool cond = ((long)th * BSZ > MAXTOK) && (th > 0) && (KBUD < th);
  int cum = 0, fb = -1;
  for (int i = 0; i < NB; ++i) {
    bool m2 = cond ? (ent[i] > kth) : m1[i];
    cum += m2 ? BSZ : 0;
    bool tf = m2 && (cum <= MAXTOK);
    bool bf = (!m1[i]) || (m2 && !tf);
    int f = tf ? 1 : (bf ? 2 : 0);
    flags[i] = f;
    if (f == 1) fb = i;
  }
  flags[NB] = fb;  // index of the (unique) token-routed block, or -1
}

// ---------------- K4: fill routing for block-routed / zero blocks ----------------
__global__ __launch_bounds__(256) void k_fill(const int* __restrict__ flags,
    const float* __restrict__ bwv, const int* __restrict__ bwi, float* __restrict__ routing) {
  int wg = blockIdx.x;
  int bn = wg >> 3, seg = wg & 7;
  int fl = flags[bn];
  if (fl == 1) return;  // token GEMM path writes these
  int b = bn >> 3, n = bn & 7;
  float4 z = make_float4(0.f, 0.f, 0.f, 0.f);
  float4 val = z;
  int c_hit = -1;
  if (fl == 2) {
    int ai = bwi[bn];
    c_hit = ai >> 2;
    ((float*)&val)[ai & 3] = bwv[bn];
  }
  float4* out = (float4*)(routing + ((size_t)(b * SS + n * BSZ + seg * 128) * EE));
  int tid = threadIdx.x;
  for (int l = 0; l < 2; ++l) {
    int idx = l * 256 + tid;  // 512 float4 = 128 rows x 4
    int c = idx & 3;
    out[idx] = (c == c_hit) ? val : z;
  }
}

// ---------------- K5: token GEMM (only the flagged block; others exit) ----------------
__global__ __launch_bounds__(256) void k_tokgemm(const float* __restrict__ x,
    const float* __restrict__ tw1, const float* __restrict__ tb1, const float* __restrict__ tw2,
    const int* __restrict__ flags, float* __restrict__ lpart) {
  int fb = flags[NB];
  if (fb < 0) return;
  int b = fb >> 3, n = fb & 7;
  int tg = blockIdx.x >> 4, nc = blockIdx.x & 15;
  int t0 = tg * 64, j0 = nc * 64;
  const float* xb = x + ((size_t)(b * SS + n * BSZ + t0) * HH);
  __shared__ float xs[64][33];
  __shared__ float wsm[32][65];
  __shared__ float ths[64][65];
  int tid = threadIdx.x;
  int tr = tid >> 4, tc = tid & 15;
  float acc[4][4];
  for (int i = 0; i < 4; ++i)
    for (int j = 0; j < 4; ++j) acc[i][j] = tb1[j0 + tc + j * 16];
  for (int k0 = 0; k0 < HH; k0 += 32) {
    for (int l = 0; l < 8; ++l) {
      int idx = l * 256 + tid; int r = idx >> 5, c = idx & 31;
      xs[r][c] = xb[(size_t)r * HH + k0 + c];
    }
    for (int l = 0; l < 8; ++l) {
      int idx = l * 256 + tid; int r = idx >> 6, c = idx & 63;
      wsm[r][c] = tw1[(size_t)(k0 + r) * HHALF + j0 + c];
    }
    __syncthreads();
    for (int kk = 0; kk < 32; ++kk) {
      float xv[4], wv[4];
      for (int i = 0; i < 4; ++i) xv[i] = xs[tr + i * 16][kk];
      for (int j = 0; j < 4; ++j) wv[j] = wsm[kk][tc + j * 16];
      for (int i = 0; i < 4; ++i)
        for (int j = 0; j < 4; ++j) acc[i][j] += xv[i] * wv[j];
    }
    __syncthreads();
  }
  // exact GELU, stash tile to LDS
  for (int i = 0; i < 4; ++i)
    for (int j = 0; j < 4; ++j) {
      float aa = acc[i][j];
      ths[tr + i * 16][tc + j * 16] = 0.5f * aa * (1.0f + erff(aa * 0.70710678f));
    }
  __syncthreads();
  // partial logits for this nc slice (deterministic, no atomics)
  float* lp = lpart + (size_t)nc * (BSZ * EE);
  for (int l = 0; l < 4; ++l) {
    int idx = l * 256 + tid; int t = idx >> 4, e = idx & 15;
    float s = 0;
    for (int jj = 0; jj < 64; ++jj) s += ths[t][jj] * tw2[(size_t)(j0 + jj) * EE + e];
    lp[(t0 + t) * EE + e] = s;
  }
}

// ---------------- K6: token softmax + routing write + usage partials ----------------
__global__ __launch_bounds__(64) void k_toksoft(const float* __restrict__ lpart,
    const float* __restrict__ tb2, const int* __restrict__ flags,
    float* __restrict__ routing, double* __restrict__ upart) {
  int fb = flags[NB];
  if (fb < 0) return;
  int b = fb >> 3, n = fb & 7;
  int w = blockIdx.x;
  int t = w * 64 + threadIdx.x;
  float l[EE];
  for (int e = 0; e < EE; ++e) {
    float s = tb2[e];
    for (int nc = 0; nc < 16; ++nc) s += lpart[(size_t)nc * (BSZ * EE) + t * EE + e];
    l[e] = s;
  }
  float mx = l[0];
  for (int e = 1; e < EE; ++e) mx = fmaxf(mx, l[e]);
  float se = 0;
  for (int e = 0; e < EE; ++e) { l[e] = expf(l[e] - mx); se += l[e]; }
  float inv = 1.0f / se;
  for (int e = 0; e < EE; ++e) l[e] *= inv;
  float4* orow = (float4*)(routing + ((size_t)(b * SS + n * BSZ + t) * EE));
  orow[0] = make_float4(l[0], l[1], l[2], l[3]);
  orow[1] = make_float4(l[4], l[5], l[6], l[7]);
  orow[2] = make_float4(l[8], l[9], l[10], l[11]);
  orow[3] = make_float4(l[12], l[13], l[14], l[15]);
  for (int e = 0; e < EE; ++e) {
    double v = (double)l[e];
    for (int o = 32; o; o >>= 1) v += __shfl_down(v, o);
    if (threadIdx.x == 0) upart[w * EE + e] = v;
  }
}

// ---------------- K7: aux KL scalar ----------------
__global__ void k_aux(const double* __restrict__ upart, const int* __restrict__ flags,
    const float* __restrict__ bwv, const int* __restrict__ bwi, float* __restrict__ outaux) {
  if (threadIdx.x != 0 || blockIdx.x != 0) return;
  double us[EE];
  for (int e = 0; e < EE; ++e) us[e] = 0;
  if (flags[NB] >= 0)
    for (int w = 0; w < 16; ++w)
      for (int e = 0; e < EE; ++e) us[e] += upart[w * EE + e];
  for (int i = 0; i < NB; ++i)
    if (flags[i] == 2) us[bwi[i]] += (double)BSZ * (double)bwv[i];
  double aux = 0;
  const double target = 1.0 / EE;
  for (int e = 0; e < EE; ++e) {
    double u = us[e] / (double)(BB * SS);
    aux += target * log(target / (u + 1e-10));
  }
  *outaux = (float)aux;
}

extern "C" void kernel_launch(void* const* d_in, const int* in_sizes, int n_in,
                              void* d_out, int out_size, void* d_ws, size_t ws_size,
                              hipStream_t stream) {
  const float* x   = (const float*)d_in[0];
  const float* bw1 = (const float*)d_in[1];
  const float* bb1 = (const float*)d_in[2];
  const float* lng = (const float*)d_in[3];
  const float* lnb = (const float*)d_in[4];
  const float* bw2 = (const float*)d_in[5];
  const float* bb2 = (const float*)d_in[6];
  const float* tw1 = (const float*)d_in[7];
  const float* tb1 = (const float*)d_in[8];
  const float* tw2 = (const float*)d_in[9];
  const float* tb2 = (const float*)d_in[10];
  float* routing = (float*)d_out;
  float* outaux = routing + (size_t)BB * SS * EE;

  char* w = (char*)d_ws;
  const size_t lpart_sz = 16 * (size_t)BSZ * EE * 4;  // 1 MB logit partials
  const size_t upart_sz = 16 * EE * 8;
  const size_t tail_sz  = lpart_sz + upart_sz + NB * 8 + 3 * 256 + 1024;
  int TC = 16;  // t-chunks per block for the mean kernel (parallelism)
  while (TC > 2 && ((size_t)NB * TC * HH * 8 + tail_sz > ws_size)) TC >>= 1;
  int rows = BSZ / TC;

  size_t off = 0;
  double* part  = (double*)(w + off); off += (size_t)NB * TC * HH * 8;
  float*  lpart = (float*) (w + off); off += lpart_sz;
  double* upart = (double*)(w + off); off += upart_sz;
  double* ent   = (double*)(w + off); off += NB * 8;
  float*  bwv   = (float*) (w + off); off += 256;
  int*    bwi   = (int*)   (w + off); off += 256;
  int*    flags = (int*)   (w + off); off += 256;

  hipLaunchKernelGGL(k_bmean,   dim3(NB * TC), dim3(256), 0, stream, x, part, TC, rows);
  hipLaunchKernelGGL(k_router,  dim3(NB),      dim3(256), 0, stream, part, TC,
                     bw1, bb1, lng, lnb, bw2, bb2, ent, bwv, bwi);
  hipLaunchKernelGGL(k_flags,   dim3(1),       dim3(1),   0, stream, ent, flags);
  hipLaunchKernelGGL(k_fill,    dim3(NB * 8),  dim3(256), 0, stream, flags, bwv, bwi, routing);
  hipLaunchKernelGGL(k_tokgemm, dim3(256),     dim3(256), 0, stream, x, tw1, tb1, tw2, flags, lpart);
  hipLaunchKernelGGL(k_toksoft, dim3(16),      dim3(64),  0, stream, lpart, tb2, flags, routing, upart);
  hipLaunchKernelGGL(k_aux,     dim3(1),       dim3(1),   0, stream, upart, flags, bwv, bwi, outaux);
}

// Round 2
// 143.546 us; speedup vs baseline: 1.3669x; 1.3669x over previous
//
#include <hip/hip_runtime.h>
#include <math.h>

#define BB 4
#define SS 8192
#define HH 2048
#define EE 16
#define BRD_ 256
#define BSZ 1024   /* block size from _adjust(8192) */
#define NN 8       /* SS/BSZ */
#define NB 32      /* BB*NN */
#define MAXTOK 1720 /* int(8192*0.21000000000000002) */
#define KBUD 1
#define HHALF 1024

// ---------------- K1: block mean partial sums (memory-bound floor) ----------------
__global__ __launch_bounds__(256) void k_bmean(const float* __restrict__ x,
                                               double* __restrict__ part, int TC, int rows) {
  int wg = blockIdx.x;
  int bn = wg / TC, tc = wg - bn * TC;
  int b = bn >> 3, n = bn & 7;
  int tid = threadIdx.x;
  const float* base = x + ((size_t)(b * SS + n * BSZ + tc * rows) * HH);
  double a0=0,a1=0,a2=0,a3=0,a4=0,a5=0,a6=0,a7=0;
  for (int t = 0; t < rows; ++t) {
    const float4* r = (const float4*)(base + (size_t)t * HH);
    float4 u = r[tid];        // h = tid*4 .. +3
    float4 v = r[tid + 256];  // h = 1024 + tid*4 .. +3
    a0 += u.x; a1 += u.y; a2 += u.z; a3 += u.w;
    a4 += v.x; a5 += v.y; a6 += v.z; a7 += v.w;
  }
  double* p = part + ((size_t)bn * TC + tc) * HH;
  int hA = tid * 4, hB = 1024 + tid * 4;
  p[hA] = a0; p[hA+1] = a1; p[hA+2] = a2; p[hA+3] = a3;
  p[hB] = a4; p[hB+1] = a5; p[hB+2] = a6; p[hB+3] = a7;
}

// ---------------- K2: block router (fp64 accumulation, latency-parallel) ----------------
__global__ __launch_bounds__(256) void k_router(const double* __restrict__ part, int TC,
    const float* __restrict__ bw1, const float* __restrict__ bb1,
    const float* __restrict__ lng, const float* __restrict__ lnb,
    const float* __restrict__ bw2, const float* __restrict__ bb2,
    double* __restrict__ ent, float* __restrict__ bwv, int* __restrict__ bwi) {
  __shared__ double br[HH];        // 16 KB block_repr (mean)
  __shared__ double p2[4][BRD_];   // 8 KB GEMM1 K-split partials
  __shared__ double tg[BRD_];      // gelu output
  __shared__ double p3[16][EE];    // GEMM2 partials
  __shared__ double red[4];
  __shared__ double l2[EE];
  __shared__ double bcast;
  int bn = blockIdx.x, tid = threadIdx.x;

  // Phase A: reduce k_bmean partials -> block mean (fp64)
  for (int k = 0; k < 8; ++k) {
    int h = tid + k * 256;
    double s = 0;
    for (int tc = 0; tc < TC; ++tc) s += part[((size_t)bn * TC + tc) * HH + h];
    br[h] = s * (1.0 / BSZ);
  }
  __syncthreads();

  // Phase B: GEMM1 [1,2048]x[2048,256]. K split 4-way across waves;
  // each thread: 4 output columns, 512 independent float4 loads, 8 fp64 accs.
  {
    int j0 = (tid & 63) * 4, kq = tid >> 6;
    const float* wp = bw1 + (size_t)(kq * 512) * BRD_ + j0;
    const double* brk = br + kq * 512;
    double a0=0,a1=0,a2=0,a3=0,c0=0,c1=0,c2=0,c3=0;
    for (int k = 0; k < 512; k += 2) {
      float4 w0 = *(const float4*)(wp + (size_t)k * BRD_);
      float4 w1 = *(const float4*)(wp + (size_t)(k + 1) * BRD_);
      double bk0 = brk[k], bk1 = brk[k + 1];
      a0 += bk0 * w0.x; a1 += bk0 * w0.y; a2 += bk0 * w0.z; a3 += bk0 * w0.w;
      c0 += bk1 * w1.x; c1 += bk1 * w1.y; c2 += bk1 * w1.z; c3 += bk1 * w1.w;
    }
    p2[kq][j0]   = a0 + c0; p2[kq][j0+1] = a1 + c1;
    p2[kq][j0+2] = a2 + c2; p2[kq][j0+3] = a3 + c3;
  }
  __syncthreads();
  double a = (double)bb1[tid] + p2[0][tid] + p2[1][tid] + p2[2][tid] + p2[3][tid];

  // LayerNorm over 256 outputs (eps=1e-5, population var)
  double v = a;
  for (int o = 32; o; o >>= 1) v += __shfl_down(v, o);
  if ((tid & 63) == 0) red[tid >> 6] = v;
  __syncthreads();
  if (tid == 0) bcast = (red[0] + red[1] + red[2] + red[3]) * (1.0 / BRD_);
  __syncthreads();
  double m = bcast;
  double d = a - m;
  v = d * d;
  for (int o = 32; o; o >>= 1) v += __shfl_down(v, o);
  if ((tid & 63) == 0) red[tid >> 6] = v;
  __syncthreads();
  if (tid == 0) bcast = (red[0] + red[1] + red[2] + red[3]) * (1.0 / BRD_);
  __syncthreads();
  double var = bcast;
  double xn = d / sqrt(var + 1e-5) * (double)lng[tid] + (double)lnb[tid];
  // exact GELU (approximate=False)
  tg[tid] = 0.5 * xn * (1.0 + erf(xn * 0.7071067811865476));
  __syncthreads();

  // Phase C: GEMM2 [1,256]x[256,16], parallel: thread = (j-chunk, expert)
  {
    int e = tid & 15, jc = tid >> 4;
    double s = 0;
    const float* w2 = bw2 + (size_t)(jc * 16) * EE + e;
    for (int j = 0; j < 16; ++j) s += tg[jc * 16 + j] * (double)w2[j * EE];
    p3[jc][e] = s;
  }
  __syncthreads();
  if (tid < EE) {
    double acc = (double)bb2[tid];
    for (int jc = 0; jc < 16; ++jc) acc += p3[jc][tid];
    l2[tid] = acc;
  }
  __syncthreads();

  if (tid == 0) {
    double mx = l2[0];
    for (int e = 1; e < EE; ++e) mx = fmax(mx, l2[e]);
    double se = 0, p[EE];
    for (int e = 0; e < EE; ++e) { p[e] = exp(l2[e] - mx); se += p[e]; }
    double inv = 1.0 / se, entv = 0, mp = -1; int ai = 0;
    for (int e = 0; e < EE; ++e) {
      double pr = p[e] * inv;
      if (pr > mp) { mp = pr; ai = e; }   // first-max, matches argmax
      double q = pr + 1e-10;
      entv -= q * log(q);
    }
    entv /= log(16.0);
    ent[bn] = entv; bwv[bn] = (float)mp; bwi[bn] = ai;
  }
}

// ---------------- K3: mask logic (serial, 32 elements) ----------------
__global__ void k_flags(const double* __restrict__ ent, int* __restrict__ flags) {
  if (threadIdx.x != 0 || blockIdx.x != 0) return;
  const double THR = 0.6 * 1.1;  // 0.66000000000000003
  bool m1[NB]; int th = 0;
  for (int i = 0; i < NB; ++i) { m1[i] = ent[i] > THR; th += m1[i] ? 1 : 0; }
  double a[NB];
  for (int i = 0; i < NB; ++i) a[i] = m1[i] ? ent[i] : -INFINITY;
  for (int i = 1; i < NB; ++i) {
    double vv = a[i]; int j = i - 1;
    while (j >= 0 && a[j] < vv) { a[j + 1] = a[j]; --j; }
    a[j + 1] = vv;
  }
  double kth = a[KBUD - 1];
  bool cond = ((long)th * BSZ > MAXTOK) && (th > 0) && (KBUD < th);
  int cum = 0, fb = -1;
  for (int i = 0; i < NB; ++i) {
    bool m2 = cond ? (ent[i] > kth) : m1[i];
    cum += m2 ? BSZ : 0;
    bool tf = m2 && (cum <= MAXTOK);
    bool bf = (!m1[i]) || (m2 && !tf);
    int f = tf ? 1 : (bf ? 2 : 0);
    flags[i] = f;
    if (f == 1) fb = i;
  }
  flags[NB] = fb;  // index of the (unique) token-routed block, or -1
}

// ---------------- K4: fill routing for block-routed / zero blocks ----------------
__global__ __launch_bounds__(256) void k_fill(const int* __restrict__ flags,
    const float* __restrict__ bwv, const int* __restrict__ bwi, float* __restrict__ routing) {
  int wg = blockIdx.x;
  int bn = wg >> 3, seg = wg & 7;
  int fl = flags[bn];
  if (fl == 1) return;  // token GEMM path writes these
  int b = bn >> 3, n = bn & 7;
  float4 z = make_float4(0.f, 0.f, 0.f, 0.f);
  float4 val = z;
  int c_hit = -1;
  if (fl == 2) {
    int ai = bwi[bn];
    c_hit = ai >> 2;
    ((float*)&val)[ai & 3] = bwv[bn];
  }
  float4* out = (float4*)(routing + ((size_t)(b * SS + n * BSZ + seg * 128) * EE));
  int tid = threadIdx.x;
  for (int l = 0; l < 2; ++l) {
    int idx = l * 256 + tid;  // 512 float4 = 128 rows x 4
    int c = idx & 3;
    out[idx] = (c == c_hit) ? val : z;
  }
}

// ---------------- K5: token GEMM (only the flagged block; others exit) ----------------
__global__ __launch_bounds__(256) void k_tokgemm(const float* __restrict__ x,
    const float* __restrict__ tw1, const float* __restrict__ tb1, const float* __restrict__ tw2,
    const int* __restrict__ flags, float* __restrict__ lpart) {
  int fb = flags[NB];
  if (fb < 0) return;
  int b = fb >> 3, n = fb & 7;
  int tg = blockIdx.x >> 4, nc = blockIdx.x & 15;
  int t0 = tg * 64, j0 = nc * 64;
  const float* xb = x + ((size_t)(b * SS + n * BSZ + t0) * HH);
  __shared__ float xs[64][33];
  __shared__ float wsm[32][65];
  __shared__ float ths[64][65];
  int tid = threadIdx.x;
  int tr = tid >> 4, tc = tid & 15;
  float acc[4][4];
  for (int i = 0; i < 4; ++i)
    for (int j = 0; j < 4; ++j) acc[i][j] = tb1[j0 + tc + j * 16];
  for (int k0 = 0; k0 < HH; k0 += 32) {
    for (int l = 0; l < 8; ++l) {
      int idx = l * 256 + tid; int r = idx >> 5, c = idx & 31;
      xs[r][c] = xb[(size_t)r * HH + k0 + c];
    }
    for (int l = 0; l < 8; ++l) {
      int idx = l * 256 + tid; int r = idx >> 6, c = idx & 63;
      wsm[r][c] = tw1[(size_t)(k0 + r) * HHALF + j0 + c];
    }
    __syncthreads();
    for (int kk = 0; kk < 32; ++kk) {
      float xv[4], wv[4];
      for (int i = 0; i < 4; ++i) xv[i] = xs[tr + i * 16][kk];
      for (int j = 0; j < 4; ++j) wv[j] = wsm[kk][tc + j * 16];
      for (int i = 0; i < 4; ++i)
        for (int j = 0; j < 4; ++j) acc[i][j] += xv[i] * wv[j];
    }
    __syncthreads();
  }
  for (int i = 0; i < 4; ++i)
    for (int j = 0; j < 4; ++j) {
      float aa = acc[i][j];
      ths[tr + i * 16][tc + j * 16] = 0.5f * aa * (1.0f + erff(aa * 0.70710678f));
    }
  __syncthreads();
  float* lp = lpart + (size_t)nc * (BSZ * EE);
  for (int l = 0; l < 4; ++l) {
    int idx = l * 256 + tid; int t = idx >> 4, e = idx & 15;
    float s = 0;
    for (int jj = 0; jj < 64; ++jj) s += ths[t][jj] * tw2[(size_t)(j0 + jj) * EE + e];
    lp[(t0 + t) * EE + e] = s;
  }
}

// ---------------- K6: token softmax + routing write + usage partials ----------------
__global__ __launch_bounds__(64) void k_toksoft(const float* __restrict__ lpart,
    const float* __restrict__ tb2, const int* __restrict__ flags,
    float* __restrict__ routing, double* __restrict__ upart) {
  int fb = flags[NB];
  if (fb < 0) return;
  int b = fb >> 3, n = fb & 7;
  int w = blockIdx.x;
  int t = w * 64 + threadIdx.x;
  float l[EE];
  for (int e = 0; e < EE; ++e) {
    float s = tb2[e];
    for (int nc = 0; nc < 16; ++nc) s += lpart[(size_t)nc * (BSZ * EE) + t * EE + e];
    l[e] = s;
  }
  float mx = l[0];
  for (int e = 1; e < EE; ++e) mx = fmaxf(mx, l[e]);
  float se = 0;
  for (int e = 0; e < EE; ++e) { l[e] = expf(l[e] - mx); se += l[e]; }
  float inv = 1.0f / se;
  for (int e = 0; e < EE; ++e) l[e] *= inv;
  float4* orow = (float4*)(routing + ((size_t)(b * SS + n * BSZ + t) * EE));
  orow[0] = make_float4(l[0], l[1], l[2], l[3]);
  orow[1] = make_float4(l[4], l[5], l[6], l[7]);
  orow[2] = make_float4(l[8], l[9], l[10], l[11]);
  orow[3] = make_float4(l[12], l[13], l[14], l[15]);
  for (int e = 0; e < EE; ++e) {
    double v = (double)l[e];
    for (int o = 32; o; o >>= 1) v += __shfl_down(v, o);
    if (threadIdx.x == 0) upart[w * EE + e] = v;
  }
}

// ---------------- K7: aux KL scalar ----------------
__global__ void k_aux(const double* __restrict__ upart, const int* __restrict__ flags,
    const float* __restrict__ bwv, const int* __restrict__ bwi, float* __restrict__ outaux) {
  if (threadIdx.x != 0 || blockIdx.x != 0) return;
  double us[EE];
  for (int e = 0; e < EE; ++e) us[e] = 0;
  if (flags[NB] >= 0)
    for (int w = 0; w < 16; ++w)
      for (int e = 0; e < EE; ++e) us[e] += upart[w * EE + e];
  for (int i = 0; i < NB; ++i)
    if (flags[i] == 2) us[bwi[i]] += (double)BSZ * (double)bwv[i];
  double aux = 0;
  const double target = 1.0 / EE;
  for (int e = 0; e < EE; ++e) {
    double u = us[e] / (double)(BB * SS);
    aux += target * log(target / (u + 1e-10));
  }
  *outaux = (float)aux;
}

extern "C" void kernel_launch(void* const* d_in, const int* in_sizes, int n_in,
                              void* d_out, int out_size, void* d_ws, size_t ws_size,
                              hipStream_t stream) {
  const float* x   = (const float*)d_in[0];
  const float* bw1 = (const float*)d_in[1];
  const float* bb1 = (const float*)d_in[2];
  const float* lng = (const float*)d_in[3];
  const float* lnb = (const float*)d_in[4];
  const float* bw2 = (const float*)d_in[5];
  const float* bb2 = (const float*)d_in[6];
  const float* tw1 = (const float*)d_in[7];
  const float* tb1 = (const float*)d_in[8];
  const float* tw2 = (const float*)d_in[9];
  const float* tb2 = (const float*)d_in[10];
  float* routing = (float*)d_out;
  float* outaux = routing + (size_t)BB * SS * EE;

  char* w = (char*)d_ws;
  const size_t lpart_sz = 16 * (size_t)BSZ * EE * 4;  // 1 MB logit partials
  const size_t upart_sz = 16 * EE * 8;
  const size_t tail_sz  = lpart_sz + upart_sz + NB * 8 + 3 * 256 + 1024;
  int TC = 16;  // t-chunks per block for the mean kernel (parallelism)
  while (TC > 2 && ((size_t)NB * TC * HH * 8 + tail_sz > ws_size)) TC >>= 1;
  int rows = BSZ / TC;

  size_t off = 0;
  double* part  = (double*)(w + off); off += (size_t)NB * TC * HH * 8;
  float*  lpart = (float*) (w + off); off += lpart_sz;
  double* upart = (double*)(w + off); off += upart_sz;
  double* ent   = (double*)(w + off); off += NB * 8;
  float*  bwv   = (float*) (w + off); off += 256;
  int*    bwi   = (int*)   (w + off); off += 256;
  int*    flags = (int*)   (w + off); off += 256;

  hipLaunchKernelGGL(k_bmean,   dim3(NB * TC), dim3(256), 0, stream, x, part, TC, rows);
  hipLaunchKernelGGL(k_router,  dim3(NB),      dim3(256), 0, stream, part, TC,
                     bw1, bb1, lng, lnb, bw2, bb2, ent, bwv, bwi);
  hipLaunchKernelGGL(k_flags,   dim3(1),       dim3(1),   0, stream, ent, flags);
  hipLaunchKernelGGL(k_fill,    dim3(NB * 8),  dim3(256), 0, stream, flags, bwv, bwi, routing);
  hipLaunchKernelGGL(k_tokgemm, dim3(256),     dim3(256), 0, stream, x, tw1, tb1, tw2, flags, lpart);
  hipLaunchKernelGGL(k_toksoft, dim3(16),      dim3(64),  0, stream, lpart, tb2, flags, routing, upart);
  hipLaunchKernelGGL(k_aux,     dim3(1),       dim3(1),   0, stream, upart, flags, bwv, bwi, outaux);
}